// Round 3
// baseline (226.947 us; speedup 1.0000x reference)
//
#include <hip/hip_runtime.h>
#include <hip/hip_bf16.h>

// out[n,a,b,f,w] = 0.75*(x[n,a,f,u]*y[n,b,f,v] + x[n,b,f,u]*y[n,a,f,v])
//                  - 0.5*z[n,f,w]*(a==b),   w = u*2+v
// N=8192, F=128, P1=P2=2. Streaming, memory-bound.
// R3: same as R2 but with native ext_vector float4 so the nontemporal
//     builtins compile (HIP_vector_type is a struct, rejected by clang).

#define NN 8192
#define FF 128

typedef float v4f __attribute__((ext_vector_type(4)));

__global__ __launch_bounds__(256) void tp_block2_kernel(
    const float* __restrict__ x,   // [N,3,F,2]
    const float* __restrict__ y,   // [N,3,F,2]
    const float* __restrict__ z,   // [N,F,4]
    float* __restrict__ out)       // [N,3,3,F,4]
{
    int t = blockIdx.x * blockDim.x + threadIdx.x;   // [0, N*64)
    int n  = t >> 6;          // t / 64
    int fh = t & 63;          // f-pair index; covers f = 2*fh, 2*fh+1
    int fp = fh << 1;

    // x viewed as v4f: element (n*3+a)*64 + fh covers
    //   .x=x[n,a,fp,0] .y=x[n,a,fp,1] .z=x[n,a,fp+1,0] .w=x[n,a,fp+1,1]
    const v4f* x4 = reinterpret_cast<const v4f*>(x);
    const v4f* y4 = reinterpret_cast<const v4f*>(y);

    v4f xa[3], ya[3];
#pragma unroll
    for (int a = 0; a < 3; ++a) {
        xa[a] = __builtin_nontemporal_load(&x4[(n * 3 + a) * 64 + fh]);
        ya[a] = __builtin_nontemporal_load(&y4[(n * 3 + a) * 64 + fh]);
    }
    // z: one v4f per f
    const v4f* z4 = reinterpret_cast<const v4f*>(z);
    v4f z0 = __builtin_nontemporal_load(&z4[n * FF + fp]);
    v4f z1 = __builtin_nontemporal_load(&z4[n * FF + fp + 1]);

    const float c  = 0.75f;   // NORM_112
    const float c2 = 0.5f;    // 0.75 * 2/3

    v4f* o4 = reinterpret_cast<v4f*>(out);   // [N,9,F] of v4f
#pragma unroll
    for (int a = 0; a < 3; ++a) {
#pragma unroll
        for (int b = 0; b < 3; ++b) {
            int g = a * 3 + b;
            v4f r0, r1;
            // f = fp  (components .x,.y of xa/ya)
            r0.x = c * (xa[a].x * ya[b].x + xa[b].x * ya[a].x);
            r0.y = c * (xa[a].x * ya[b].y + xa[b].x * ya[a].y);
            r0.z = c * (xa[a].y * ya[b].x + xa[b].y * ya[a].x);
            r0.w = c * (xa[a].y * ya[b].y + xa[b].y * ya[a].y);
            // f = fp+1 (components .z,.w)
            r1.x = c * (xa[a].z * ya[b].z + xa[b].z * ya[a].z);
            r1.y = c * (xa[a].z * ya[b].w + xa[b].z * ya[a].w);
            r1.z = c * (xa[a].w * ya[b].z + xa[b].w * ya[a].z);
            r1.w = c * (xa[a].w * ya[b].w + xa[b].w * ya[a].w);
            if (a == b) {
                r0.x -= c2 * z0.x; r0.y -= c2 * z0.y;
                r0.z -= c2 * z0.z; r0.w -= c2 * z0.w;
                r1.x -= c2 * z1.x; r1.y -= c2 * z1.y;
                r1.z -= c2 * z1.z; r1.w -= c2 * z1.w;
            }
            __builtin_nontemporal_store(r0, &o4[(n * 9 + g) * FF + fp]);
            __builtin_nontemporal_store(r1, &o4[(n * 9 + g) * FF + fp + 1]);
        }
    }
}

extern "C" void kernel_launch(void* const* d_in, const int* in_sizes, int n_in,
                              void* d_out, int out_size, void* d_ws, size_t ws_size,
                              hipStream_t stream) {
    const float* x = (const float*)d_in[0];
    const float* y = (const float*)d_in[1];
    const float* z = (const float*)d_in[2];
    // d_in[3] is eye(3) — identity by construction, folded into the kernel.
    float* out = (float*)d_out;

    const int total = NN * 64;                 // 524,288 threads (2 f each)
    const int block = 256;
    const int grid = total / block;            // 2048 blocks
    tp_block2_kernel<<<grid, block, 0, stream>>>(x, y, z, out);
}

// Round 4
// 201.743 us; speedup vs baseline: 1.1249x; 1.1249x over previous
//
#include <hip/hip_runtime.h>
#include <hip/hip_bf16.h>

// out[n,a,b,f,w] = 0.75*(x[n,a,f,u]*y[n,b,f,v] + x[n,b,f,u]*y[n,a,f,v])
//                  - 0.5*z[n,f,w]*(a==b),   w = u*2+v
// N=8192, F=128, P1=P2=2. Streaming, memory-bound.
// R4: R1's mapping (1 thread per (n,f) — every load/store lane-dense and
//     coalesced; R3's 2-f mapping made stores stride-32B = 2x transactions)
//     + nontemporal hints via ext_vector types (all streams single-touch).

#define NN 8192
#define FF 128

typedef float v2f __attribute__((ext_vector_type(2)));
typedef float v4f __attribute__((ext_vector_type(4)));

__global__ __launch_bounds__(256) void tp_block2_kernel(
    const float* __restrict__ x,   // [N,3,F,2]
    const float* __restrict__ y,   // [N,3,F,2]
    const float* __restrict__ z,   // [N,F,4]
    float* __restrict__ out)       // [N,3,3,F,4]
{
    int t = blockIdx.x * blockDim.x + threadIdx.x;   // [0, N*F)
    int n = t >> 7;     // t / F
    int f = t & 127;    // t % F

    // x,y viewed as v2f over the trailing P dim: index (n*3 + a)*F + f
    const v2f* x2p = reinterpret_cast<const v2f*>(x);
    const v2f* y2p = reinterpret_cast<const v2f*>(y);

    v2f xa[3], ya[3];
#pragma unroll
    for (int a = 0; a < 3; ++a) {
        xa[a] = __builtin_nontemporal_load(&x2p[(n * 3 + a) * FF + f]);
        ya[a] = __builtin_nontemporal_load(&y2p[(n * 3 + a) * FF + f]);
    }
    const v4f* z4 = reinterpret_cast<const v4f*>(z);
    v4f zz = __builtin_nontemporal_load(&z4[n * FF + f]);

    const float c  = 0.75f;   // NORM_112
    const float c2 = 0.5f;    // 0.75 * 2/3

    v4f* outp = reinterpret_cast<v4f*>(out);  // [N,3,3,F] of v4f
#pragma unroll
    for (int a = 0; a < 3; ++a) {
#pragma unroll
        for (int b = 0; b < 3; ++b) {
            v4f r;
            // w = u*2 + v ; .x=(0,0) .y=(0,1) .z=(1,0) .w=(1,1)
            r.x = c * (xa[a].x * ya[b].x + xa[b].x * ya[a].x);
            r.y = c * (xa[a].x * ya[b].y + xa[b].x * ya[a].y);
            r.z = c * (xa[a].y * ya[b].x + xa[b].y * ya[a].x);
            r.w = c * (xa[a].y * ya[b].y + xa[b].y * ya[a].y);
            if (a == b) {
                r.x -= c2 * zz.x;
                r.y -= c2 * zz.y;
                r.z -= c2 * zz.z;
                r.w -= c2 * zz.w;
            }
            __builtin_nontemporal_store(r, &outp[(n * 9 + a * 3 + b) * FF + f]);
        }
    }
}

extern "C" void kernel_launch(void* const* d_in, const int* in_sizes, int n_in,
                              void* d_out, int out_size, void* d_ws, size_t ws_size,
                              hipStream_t stream) {
    const float* x = (const float*)d_in[0];
    const float* y = (const float*)d_in[1];
    const float* z = (const float*)d_in[2];
    // d_in[3] is eye(3) — identity by construction, folded into the kernel.
    float* out = (float*)d_out;

    const int total = NN * FF;                 // 1,048,576 threads
    const int block = 256;
    const int grid = total / block;            // 4096 blocks
    tp_block2_kernel<<<grid, block, 0, stream>>>(x, y, z, out);
}

// Round 5
// 200.204 us; speedup vs baseline: 1.1336x; 1.0077x over previous
//
#include <hip/hip_runtime.h>
#include <hip/hip_bf16.h>

// out[n,a,b,f,w] = 0.75*(x[n,a,f,u]*y[n,b,f,v] + x[n,b,f,u]*y[n,a,f,v])
//                  - 0.5*z[n,f,w]*(a==b),   w = u*2+v
// N=8192, F=128, P1=P2=2. Streaming, memory-bound.
// R5: same store pattern as R4 (dense 16B/lane). Load-side: adjacent lanes
//     pair up — even lane loads dwordx4 of x covering (f,f+1), odd lane the
//     matching dwordx4 of y; one 8B shfl_xor(1) per a redistributes. Cuts
//     VMEM instrs 16 -> 13 per thread to test the VMEM-issue-bound theory.

#define NN 8192
#define FF 128

typedef float v2f __attribute__((ext_vector_type(2)));
typedef float v4f __attribute__((ext_vector_type(4)));

__global__ __launch_bounds__(256) void tp_block2_kernel(
    const float* __restrict__ x,   // [N,3,F,2]
    const float* __restrict__ y,   // [N,3,F,2]
    const float* __restrict__ z,   // [N,F,4]
    float* __restrict__ out)       // [N,3,3,F,4]
{
    int t = blockIdx.x * blockDim.x + threadIdx.x;   // [0, N*F)
    int n  = t >> 7;     // t / F   (wave-uniform: a wave spans 64 f's)
    int f  = t & 127;    // t % F
    int fh = f >> 1;     // f-pair index
    bool odd = (f & 1);

    const v4f* x4 = reinterpret_cast<const v4f*>(x);
    const v4f* y4 = reinterpret_cast<const v4f*>(y);

    v2f xa[3], ya[3];
#pragma unroll
    for (int a = 0; a < 3; ++a) {
        // even lane: V = x[n,a,f..f+1,:]   odd lane: V = y[n,a,f-1..f,:]
        const v4f* base = odd ? y4 : x4;
        v4f V = __builtin_nontemporal_load(&base[(n * 3 + a) * 64 + fh]);
        // even needs partner's V.xy (= y[f]); odd needs partner's V.zw (= x[f])
        float sx = odd ? V.x : V.z;
        float sy = odd ? V.y : V.w;
        float rx = __shfl_xor(sx, 1, 64);
        float ry = __shfl_xor(sy, 1, 64);
        xa[a].x = odd ? rx : V.x;   xa[a].y = odd ? ry : V.y;
        ya[a].x = odd ? V.z : rx;   ya[a].y = odd ? V.w : ry;
    }
    const v4f* z4 = reinterpret_cast<const v4f*>(z);
    v4f zz = __builtin_nontemporal_load(&z4[n * FF + f]);

    const float c  = 0.75f;   // NORM_112
    const float c2 = 0.5f;    // 0.75 * 2/3

    v4f* outp = reinterpret_cast<v4f*>(out);  // [N,3,3,F] of v4f
#pragma unroll
    for (int a = 0; a < 3; ++a) {
#pragma unroll
        for (int b = 0; b < 3; ++b) {
            v4f r;
            // w = u*2 + v ; .x=(0,0) .y=(0,1) .z=(1,0) .w=(1,1)
            r.x = c * (xa[a].x * ya[b].x + xa[b].x * ya[a].x);
            r.y = c * (xa[a].x * ya[b].y + xa[b].x * ya[a].y);
            r.z = c * (xa[a].y * ya[b].x + xa[b].y * ya[a].x);
            r.w = c * (xa[a].y * ya[b].y + xa[b].y * ya[a].y);
            if (a == b) {
                r.x -= c2 * zz.x;
                r.y -= c2 * zz.y;
                r.z -= c2 * zz.z;
                r.w -= c2 * zz.w;
            }
            __builtin_nontemporal_store(r, &outp[(n * 9 + a * 3 + b) * FF + f]);
        }
    }
}

extern "C" void kernel_launch(void* const* d_in, const int* in_sizes, int n_in,
                              void* d_out, int out_size, void* d_ws, size_t ws_size,
                              hipStream_t stream) {
    const float* x = (const float*)d_in[0];
    const float* y = (const float*)d_in[1];
    const float* z = (const float*)d_in[2];
    // d_in[3] is eye(3) — identity by construction, folded into the kernel.
    float* out = (float*)d_out;

    const int total = NN * FF;                 // 1,048,576 threads
    const int block = 256;
    const int grid = total / block;            // 4096 blocks
    tp_block2_kernel<<<grid, block, 0, stream>>>(x, y, z, out);
}